// Round 15
// baseline (202.607 us; speedup 1.0000x reference)
//
#include <hip/hip_runtime.h>
#include <float.h>

#define BB 4
#define PP 1024
#define DD 1024
#define RR 256
#define SSZ 256
#define KT 4
#define EE 4096
#define NPAIR 3

typedef float  f32x4  __attribute__((ext_vector_type(4)));
typedef short  short8 __attribute__((ext_vector_type(8)));

#define MFMA16(a,b,c) __builtin_amdgcn_mfma_f32_16x16x32_bf16((a),(b),(c),0,0,0)
#define GLOAD_LDS(g, l) __builtin_amdgcn_global_load_lds( \
    (const __attribute__((address_space(1))) void*)(g),   \
    (__attribute__((address_space(3))) void*)(l), 16, 0, 0)

// ---- float-region offsets (in floats) ----
#define OFF_NE    ((size_t)0)         // BB*EE
#define OFF_RR_T  ((size_t)16384)     // BB*RR
#define OFF_RR_S  ((size_t)17408)
#define OFF_HH    ((size_t)18432)     // BB*RR*KT
#define OFF_RH_T  ((size_t)22528)
#define OFF_RH_S  ((size_t)26624)
#define OFF_SS_T  ((size_t)30720)     // NPAIR*BB*SSZ
#define OFF_SS_S  ((size_t)33792)
#define OFF_TOPK  ((size_t)36864)     // BB*RR*KT ints
#define OFF_ACC   ((size_t)40960)     // double
#define OFF_CAND  ((size_t)45056)     // BB*RR*64*4 float2 = 524288 floats
#define FLOAT_END ((size_t)569344)

// ---- ushort (bf16 hi) region offsets (in ushorts), base = ws + FLOAT_END ----
#define U_REF_T ((size_t)0)           // BB*RR*DD
#define U_REF_S ((size_t)2097152)
#define U_SIMH  ((size_t)4194304)     // BB*RR*KT*DD
#define U_SH_T  ((size_t)8388608)     // NPAIR*BB*SSZ*DD
#define U_SH_S  ((size_t)11534336)
#define U_EXT   ((size_t)14680064)    // BB*EE*DD
// end 31457280 ushorts; total ws ~65.2 MB

__device__ inline float block_sum256(float v, float* sb) {
  v += __shfl_down(v, 32); v += __shfl_down(v, 16);
  v += __shfl_down(v, 8);  v += __shfl_down(v, 4);
  v += __shfl_down(v, 2);  v += __shfl_down(v, 1);
  int lane = threadIdx.x & 63, wid = threadIdx.x >> 6;
  if (lane == 0) sb[wid] = v;
  __syncthreads();
  float r = 0.f;
  if (threadIdx.x < 4) r = sb[threadIdx.x];
  r += __shfl_down(r, 2); r += __shfl_down(r, 1);
  __syncthreads();
  return r;   // valid on thread 0
}

__device__ inline float dot4(const float4& a, const float4& b) {
  return a.x*b.x + a.y*b.y + a.z*b.z + a.w*b.w;
}

// round-to-nearest-even bf16
__device__ inline unsigned short bhi(float x) {
  unsigned u = __float_as_uint(x);
  return (unsigned short)((u + 0x7fffu + ((u >> 16) & 1u)) >> 16);
}
__device__ inline ushort4 h4of(float4 f) {
  return make_ushort4(bhi(f.x), bhi(f.y), bhi(f.z), bhi(f.w));
}

// ---- fused prep: gather_ref (0..1023) | ne (1024..17407) | ss (17408..20479) ----
__global__ __launch_bounds__(256) void k_prep(const float* __restrict__ T,
                                              const float* __restrict__ Sf,
                                              const int* __restrict__ ref_perm,
                                              const int* __restrict__ shared_perm,
                                              float* __restrict__ ws) {
  __shared__ float sb[4];
  ushort* uws = (ushort*)(ws + FLOAT_END);
  int blk = blockIdx.x;
  int t = threadIdx.x;
  if (blk < 1024) {
    int b = blk >> 8, r = blk & 255;
    int pos = ref_perm[r];
    const float4* ts = (const float4*)(T  + ((size_t)(b*8 + 0)*PP + pos)*DD);
    const float4* sv = (const float4*)(Sf + ((size_t)(b*4 + 0)*PP + pos)*DD);
    float4 a = ts[t], c = sv[t];
    size_t base = ((size_t)b*RR + r)*DD + t*4;
    *(ushort4*)(uws + U_REF_T + base) = h4of(a);
    *(ushort4*)(uws + U_REF_S + base) = h4of(c);
    float r1 = block_sum256(dot4(a, a), sb);
    float r2 = block_sum256(dot4(c, c), sb);
    if (t == 0) {
      ws[OFF_RR_T + b*RR + r] = r1;
      ws[OFF_RR_S + b*RR + r] = r2;
    }
  } else if (blk < 17408) {
    int i = blk - 1024;
    int b = i >> 12, e = i & 4095;
    int f = 1 + 2*(e >> 10);
    int pos = e & 1023;
    const float4* src = (const float4*)(T + ((size_t)(b*8 + f)*PP + pos)*DD);
    float4 a = src[t];
    *(ushort4*)(uws + U_EXT + ((size_t)b*EE + e)*DD + t*4) = h4of(a);
    float tot = block_sum256(dot4(a, a), sb);
    if (t == 0) ws[OFF_NE + (size_t)b*EE + e] = fmaxf(sqrtf(tot), 1e-12f);
  } else {
    int idx = blk - 17408;                 // z*SSZ + s
    int p = idx / (BB*SSZ);
    int b = (idx / SSZ) % BB;
    int s = idx % SSZ;
    int pos = shared_perm[s];
    int ti = 2*(p + 1), si = p + 1;
    const float4* tr = (const float4*)(T  + ((size_t)(b*8 + ti)*PP + pos)*DD);
    const float4* sr = (const float4*)(Sf + ((size_t)(b*4 + si)*PP + pos)*DD);
    float4 a = tr[t], c = sr[t];
    size_t base = (size_t)idx*DD + t*4;
    *(ushort4*)(uws + U_SH_T + base) = h4of(a);
    *(ushort4*)(uws + U_SH_S + base) = h4of(c);
    float r1 = block_sum256(dot4(a, a), sb);
    float r2 = block_sum256(dot4(c, c), sb);
    if (t == 0) { ws[OFF_SS_T + idx] = r1; ws[OFF_SS_S + idx] = r2; }
  }
}

// ---- sim GEMM: 2-phase double-buffered gload_lds staging + fused top-4 ----
// Tile rows: [0..63] ref_t(r0+row), [64..127] ext(e0+row-64). BK=32, 32 steps.
__global__ __launch_bounds__(256) void k_sim(float* __restrict__ ws) {
  __shared__ union SM {
    ushort stg[2][128][32];    // 16 KB
    float simv[64][68];        // 17.4 KB epilogue
  } sm;
  const ushort* uws = (const ushort*)(ws + FLOAT_END);
  int e0 = blockIdx.x * 64, r0 = blockIdx.y * 64, b = blockIdx.z;
  int tid = threadIdx.x;
  int w = tid >> 6, lane = tid & 63;
  int l15 = tid & 15, lq = (tid >> 4) & 3;

  const ushort* gsrc[2];
#pragma unroll
  for (int seg = 0; seg < 2; ++seg) {
    int rt = 32*w + 16*seg + (lane >> 2);
    const ushort* base; size_t rowg;
    if (rt < 64) { base = uws + U_REF_T; rowg = (size_t)(b*RR + r0 + rt); }
    else         { base = uws + U_EXT;   rowg = (size_t)(b*EE + e0 + rt - 64); }
    int c_log = (lane & 3) ^ ((rt >> 1) & 3);
    gsrc[seg] = base + rowg*DD + c_log*8;
  }

  // preload norms (before K-loop: keeps vmcnt bookkeeping clean)
  float invs[4];
#pragma unroll
  for (int j = 0; j < 4; ++j)
    invs[j] = 1.f / ws[OFF_NE + (size_t)b*EE + e0 + j*16 + l15];

  f32x4 acc[4];
#pragma unroll
  for (int j = 0; j < 4; ++j) acc[j] = (f32x4){0.f, 0.f, 0.f, 0.f};

  // prologue stage
  GLOAD_LDS(gsrc[0], &sm.stg[0][32*w][0]);
  GLOAD_LDS(gsrc[1], &sm.stg[0][32*w + 16][0]);
  gsrc[0] += 32; gsrc[1] += 32;

  int cur = 0;
#pragma unroll 1
  for (int k0 = 0; k0 < 32; ++k0) {
    if (k0 < 31) {
      GLOAD_LDS(gsrc[0], &sm.stg[cur ^ 1][32*w][0]);
      GLOAD_LDS(gsrc[1], &sm.stg[cur ^ 1][32*w + 16][0]);
      gsrc[0] += 32; gsrc[1] += 32;
      asm volatile("s_waitcnt vmcnt(2)" ::: "memory");
    } else {
      asm volatile("s_waitcnt vmcnt(0)" ::: "memory");
    }
    __builtin_amdgcn_s_barrier();
    __builtin_amdgcn_sched_barrier(0);
    int rtA = w*16 + l15;
    short8 ah = *(const short8*)&sm.stg[cur][rtA][(lq ^ ((rtA >> 1) & 3))*8];
#pragma unroll
    for (int j = 0; j < 4; ++j) {
      int rtB = 64 + j*16 + l15;
      short8 bh = *(const short8*)&sm.stg[cur][rtB][(lq ^ ((rtB >> 1) & 3))*8];
      acc[j] = MFMA16(ah, bh, acc[j]);
    }
    __builtin_amdgcn_sched_barrier(0);
    __builtin_amdgcn_s_barrier();
    cur ^= 1;
  }

#pragma unroll
  for (int j = 0; j < 4; ++j) {
    int e_loc = j*16 + l15;
#pragma unroll
    for (int q = 0; q < 4; ++q)
      sm.simv[w*16 + lq*4 + q][e_loc] = acc[j][q] * invs[j];
  }
  __syncthreads();
  if (tid < 64) {
    float v[4] = {-FLT_MAX, -FLT_MAX, -FLT_MAX, -FLT_MAX};
    int ix[4] = {0x7fffffff, 0x7fffffff, 0x7fffffff, 0x7fffffff};
#pragma unroll 1
    for (int e = 0; e < 64; ++e) {
      float f = sm.simv[tid][e];
      if (f > v[3]) {
        int eg = e0 + e;
        if (f > v[0])      { v[3]=v[2]; ix[3]=ix[2]; v[2]=v[1]; ix[2]=ix[1]; v[1]=v[0]; ix[1]=ix[0]; v[0]=f; ix[0]=eg; }
        else if (f > v[1]) { v[3]=v[2]; ix[3]=ix[2]; v[2]=v[1]; ix[2]=ix[1]; v[1]=f; ix[1]=eg; }
        else if (f > v[2]) { v[3]=v[2]; ix[3]=ix[2]; v[2]=f; ix[2]=eg; }
        else               { v[3]=f; ix[3]=eg; }
      }
    }
    float2* cand = (float2*)(ws + OFF_CAND);
    size_t base = (((size_t)(b*RR + r0 + tid))*64 + blockIdx.x)*4;
#pragma unroll
    for (int k = 0; k < 4; ++k)
      cand[base + k] = make_float2(v[k], __int_as_float(ix[k]));
  }
}

// ---- merge 256 candidates -> top-4 per (b,r), ties -> lower global index ----
__global__ __launch_bounds__(256) void k_topk2(float* __restrict__ ws) {
  __shared__ float rv[256];
  __shared__ int   ri[256];
  __shared__ int   winIdx;
  int br = blockIdx.x;
  int tid = threadIdx.x;
  const float2* cand = (const float2*)(ws + OFF_CAND);
  float2 c = cand[(size_t)br*256 + tid];
  float v = c.x;
  int idx = __float_as_int(c.y);
  int* outi = (int*)(ws + OFF_TOPK) + (size_t)br*KT;
  for (int k = 0; k < KT; ++k) {
    rv[tid] = v; ri[tid] = idx;
    __syncthreads();
    for (int off = 128; off > 0; off >>= 1) {
      if (tid < off) {
        float v2 = rv[tid+off]; int i2 = ri[tid+off];
        if (v2 > rv[tid] || (v2 == rv[tid] && i2 < ri[tid])) { rv[tid] = v2; ri[tid] = i2; }
      }
      __syncthreads();
    }
    if (tid == 0) { outi[k] = ri[0]; winIdx = ri[0]; }
    __syncthreads();
    if (idx == winIdx) v = -FLT_MAX;
    __syncthreads();
  }
}

// ---- gather selected rows: bf16 store + hh / rh_t / rh_s (fp32) ----
__global__ __launch_bounds__(256) void k_gather_high(const float* __restrict__ T,
                                                     const float* __restrict__ Sf,
                                                     const int* __restrict__ ref_perm,
                                                     float* __restrict__ ws) {
  __shared__ float sb[4];
  int idx = blockIdx.x;                        // (b*RR + r)*KT + k
  int e = ((const int*)(ws + OFF_TOPK))[idx];
  int b = idx >> 10;
  int r = (idx >> 2) & 255;
  int rpos = ref_perm[r];
  const float4* src = (const float4*)(T + ((size_t)(b*8 + 1 + 2*(e >> 10))*PP + (e & 1023))*DD);
  const float4* rt  = (const float4*)(T  + ((size_t)(b*8 + 0)*PP + rpos)*DD);
  const float4* rs  = (const float4*)(Sf + ((size_t)(b*4 + 0)*PP + rpos)*DD);
  ushort* uws = (ushort*)(ws + FLOAT_END);
  int t = threadIdx.x;
  float4 h = src[t];
  *(ushort4*)(uws + U_SIMH + (size_t)idx*DD + t*4) = h4of(h);
  float4 a = rt[t], c = rs[t];
  float r1 = block_sum256(dot4(h, h), sb);
  float r2 = block_sum256(dot4(h, a), sb);
  float r3 = block_sum256(dot4(h, c), sb);
  if (t == 0) { ws[OFF_HH + idx] = r1; ws[OFF_RH_T + idx] = r2; ws[OFF_RH_S + idx] = r3; }
}

// ---- main fused kernel: r16 x s16 tiles, 256 threads, 8 blocks/CU ----
// Tile rows (128): [0..63] simh (r-local x 4k), [64..79] ref_t, [80..95] ref_s,
//                  [96..111] sh_t, [112..127] sh_s.  BK=32, 32 steps.
// Wave w (g=w&1, nh=w>>1): A-frags 3g..3g+2, B-frag = side nh. 3 MFMA/wave/step.
__global__ __launch_bounds__(256) void k_main(float* __restrict__ ws,
                                              double* __restrict__ acc_out) {
  __shared__ union SM {
    ushort stg[2][128][32];                              // 16 KB
    struct { float Ct[96][17]; float Cs2[96][17]; } c;   // 13 KB epilogue
  } sm;
  __shared__ float sb[4];
  const ushort* uws = (const ushort*)(ws + FLOAT_END);

  int d = blockIdx.x;
  int u = d % 24, q = d / 24;            // u -> XCD-pinned (z, r-half); q -> (r_loc, s_t)
  int z = u >> 1;
  int b = z & 3;
  int r_t = (u & 1)*8 + (q >> 4);        // 0..15
  int s_t = q & 15;                      // 0..15
  int s0 = s_t*16, r0 = r_t*16;
  int tid = threadIdx.x;
  int w = tid >> 6, lane = tid & 63;
  int l15 = tid & 15, lq = (tid >> 4) & 3;
  int g = w & 1, nh = w >> 1;

  // staging sources: wave w covers tile rows 32w..32w+31 (2 units of 16)
  const ushort* gsrc[2];
#pragma unroll
  for (int seg = 0; seg < 2; ++seg) {
    int rt = 32*w + 16*seg + (lane >> 2);
    const ushort* base; size_t rowg;
    if (rt < 64)       { base = uws + U_SIMH;  rowg = (size_t)((b*RR + r0)*4 + rt); }
    else if (rt < 80)  { base = uws + U_REF_T; rowg = (size_t)(b*RR + r0 + rt - 64); }
    else if (rt < 96)  { base = uws + U_REF_S; rowg = (size_t)(b*RR + r0 + rt - 80); }
    else if (rt < 112) { base = uws + U_SH_T;  rowg = (size_t)(z*SSZ + s0 + rt - 96); }
    else               { base = uws + U_SH_S;  rowg = (size_t)(z*SSZ + s0 + rt - 112); }
    int c_log = (lane & 3) ^ ((rt >> 1) & 3);
    gsrc[seg] = base + rowg*DD + c_log*8;
  }

  // ---- epilogue scalars preloaded BEFORE the K-loop (clean vmcnt) ----
  int rl = tid >> 4, sl = tid & 15;      // rl 0..15, sl 0..15
  int r = r0 + rl;
  float rrt = ws[OFF_RR_T + b*RR + r];
  float rrs = ws[OFF_RR_S + b*RR + r];
  float hhk[4], rhtk[4], rhsk[4], ihr_t[4], ihr_s[4];
#pragma unroll
  for (int k = 0; k < 4; ++k) {
    int idx = (b*RR + r)*KT + k;
    hhk[k]  = ws[OFF_HH + idx];
    rhtk[k] = ws[OFF_RH_T + idx];
    rhsk[k] = ws[OFF_RH_S + idx];
    float nt = sqrtf(fmaxf(hhk[k] - 2.f*rhtk[k] + rrt, 0.f));
    float ns = sqrtf(fmaxf(hhk[k] - 2.f*rhsk[k] + rrs, 0.f));
    ihr_t[k] = 1.f / fmaxf(nt, 1e-8f);
    ihr_s[k] = 1.f / fmaxf(ns, 1e-8f);
  }
  int sidx = z*SSZ + s0 + sl;
  float sst = ws[OFF_SS_T + sidx];
  float sss = ws[OFF_SS_S + sidx];

  f32x4 acc[3];
#pragma unroll
  for (int i = 0; i < 3; ++i) acc[i] = (f32x4){0.f, 0.f, 0.f, 0.f};

  // prologue stage into buf 0
  GLOAD_LDS(gsrc[0], &sm.stg[0][32*w][0]);
  GLOAD_LDS(gsrc[1], &sm.stg[0][32*w + 16][0]);
  gsrc[0] += 32; gsrc[1] += 32;

  int cur = 0;
#pragma unroll 1
  for (int k0 = 0; k0 < 32; ++k0) {
    if (k0 < 31) {
      GLOAD_LDS(gsrc[0], &sm.stg[cur ^ 1][32*w][0]);
      GLOAD_LDS(gsrc[1], &sm.stg[cur ^ 1][32*w + 16][0]);
      gsrc[0] += 32; gsrc[1] += 32;
      asm volatile("s_waitcnt vmcnt(2)" ::: "memory");
    } else {
      asm volatile("s_waitcnt vmcnt(0)" ::: "memory");
    }
    __builtin_amdgcn_s_barrier();
    __builtin_amdgcn_sched_barrier(0);
    short8 ah[3], bh;
#pragma unroll
    for (int i = 0; i < 3; ++i) {
      int rt = (3*g + i)*16 + l15;
      ah[i] = *(const short8*)&sm.stg[cur][rt][(lq ^ ((rt >> 1) & 3))*8];
    }
    {
      int rt = 96 + nh*16 + l15;
      bh = *(const short8*)&sm.stg[cur][rt][(lq ^ ((rt >> 1) & 3))*8];
    }
#pragma unroll
    for (int i = 0; i < 3; ++i)
      acc[i] = MFMA16(ah[i], bh, acc[i]);
    __builtin_amdgcn_sched_barrier(0);
    __builtin_amdgcn_s_barrier();
    cur ^= 1;
  }

  // C -> LDS (union reuse; final K-loop barrier guarantees staging reads done)
  __syncthreads();
#pragma unroll
  for (int i = 0; i < 3; ++i)
#pragma unroll
    for (int qq = 0; qq < 4; ++qq) {
      int row = (3*g + i)*16 + lq*4 + qq;
      if (nh == 0) sm.c.Ct[row][l15]  = acc[i][qq];
      else         sm.c.Cs2[row][l15] = acc[i][qq];
    }
  __syncthreads();

  float local = 0.f;
  {
    float srt = sm.c.Ct[64 + rl][sl];
    float srs = sm.c.Cs2[80 + rl][sl];
    float isr_t = 1.f / fmaxf(sqrtf(fmaxf(sst - 2.f*srt + rrt, 0.f)), 1e-8f);
    float isr_s = 1.f / fmaxf(sqrtf(fmaxf(sss - 2.f*srs + rrs, 0.f)), 1e-8f);
#pragma unroll
    for (int k = 0; k < 4; ++k) {
      float sht = sm.c.Ct[rl*4 + k][sl];
      float shs = sm.c.Cs2[rl*4 + k][sl];
      float ish_t = 1.f / fmaxf(sqrtf(fmaxf(sst - 2.f*sht + hhk[k], 0.f)), 1e-8f);
      float ish_s = 1.f / fmaxf(sqrtf(fmaxf(sss - 2.f*shs + hhk[k], 0.f)), 1e-8f);
      float a1t = (sht - rhtk[k] - srt + rrt) * (isr_t * ihr_t[k]);
      float a2t = (srt - sht - rhtk[k] + hhk[k]) * (ihr_t[k] * ish_t);
      float a3t = (rhtk[k] - srt - sht + sst) * (isr_t * ish_t);
      float a1s = (shs - rhsk[k] - srs + rrs) * (isr_s * ihr_s[k]);
      float a2s = (srs - shs - rhsk[k] + hhk[k]) * (ihr_s[k] * ish_s);
      float a3s = (rhsk[k] - srs - shs + sss) * (isr_s * ish_s);
      local += fabsf(a1s - a1t) + fabsf(a2s - a2t) + fabsf(a3s - a3t);
    }
  }
  float tot = block_sum256(local, sb);
  if (tid == 0) atomicAdd(acc_out, (double)tot);
}

__global__ void k_final(const double* __restrict__ acc, float* __restrict__ out) {
  out[0] = (float)(acc[0] / 3145728.0);   // 3 * B * R * S * K
}

extern "C" void kernel_launch(void* const* d_in, const int* in_sizes, int n_in,
                              void* d_out, int out_size, void* d_ws, size_t ws_size,
                              hipStream_t stream) {
  const float* T  = (const float*)d_in[0];
  const float* Sf = (const float*)d_in[1];
  const int* ref_perm    = (const int*)d_in[2];
  const int* shared_perm = (const int*)d_in[3];
  float* ws = (float*)d_ws;
  double* acc = (double*)(ws + OFF_ACC);

  hipMemsetAsync(acc, 0, sizeof(double), stream);
  k_prep<<<20480, 256, 0, stream>>>(T, Sf, ref_perm, shared_perm, ws);
  dim3 g1(EE/64, RR/64, BB);
  k_sim<<<g1, 256, 0, stream>>>(ws);
  k_topk2<<<BB*RR, 256, 0, stream>>>(ws);
  k_gather_high<<<BB*RR*KT, 256, 0, stream>>>(T, Sf, ref_perm, ws);
  k_main<<<3072, 256, 0, stream>>>(ws, acc);
  k_final<<<1, 1, 0, stream>>>(acc, (float*)d_out);
}

// Round 16
// 171.916 us; speedup vs baseline: 1.1785x; 1.1785x over previous
//
#include <hip/hip_runtime.h>
#include <float.h>

#define BB 4
#define PP 1024
#define DD 1024
#define RR 256
#define SSZ 256
#define KT 4
#define EE 4096
#define NPAIR 3

typedef float  f32x4  __attribute__((ext_vector_type(4)));
typedef short  short8 __attribute__((ext_vector_type(8)));

#define MFMA16(a,b,c) __builtin_amdgcn_mfma_f32_16x16x32_bf16((a),(b),(c),0,0,0)
#define GLOAD_LDS(g, l) __builtin_amdgcn_global_load_lds( \
    (const __attribute__((address_space(1))) void*)(g),   \
    (__attribute__((address_space(3))) void*)(l), 16, 0, 0)

// ---- float-region offsets (in floats) ----
#define OFF_NE    ((size_t)0)         // BB*EE
#define OFF_RR_T  ((size_t)16384)     // BB*RR
#define OFF_RR_S  ((size_t)17408)
#define OFF_HH    ((size_t)18432)     // BB*RR*KT
#define OFF_RH_T  ((size_t)22528)
#define OFF_RH_S  ((size_t)26624)
#define OFF_SS_T  ((size_t)30720)     // NPAIR*BB*SSZ
#define OFF_SS_S  ((size_t)33792)
#define OFF_TOPK  ((size_t)36864)     // BB*RR*KT ints
#define OFF_ACC   ((size_t)40960)     // double
#define OFF_CAND  ((size_t)45056)     // BB*RR*64*4 float2 = 524288 floats
#define FLOAT_END ((size_t)569344)

// ---- ushort (bf16 hi) region offsets (in ushorts), base = ws + FLOAT_END ----
#define U_REF_T ((size_t)0)           // BB*RR*DD
#define U_REF_S ((size_t)2097152)
#define U_SIMH  ((size_t)4194304)     // BB*RR*KT*DD
#define U_SH_T  ((size_t)8388608)     // NPAIR*BB*SSZ*DD
#define U_SH_S  ((size_t)11534336)
#define U_EXT   ((size_t)14680064)    // BB*EE*DD
// end 31457280 ushorts; total ws ~65.2 MB

__device__ inline float block_sum256(float v, float* sb) {
  v += __shfl_down(v, 32); v += __shfl_down(v, 16);
  v += __shfl_down(v, 8);  v += __shfl_down(v, 4);
  v += __shfl_down(v, 2);  v += __shfl_down(v, 1);
  int lane = threadIdx.x & 63, wid = threadIdx.x >> 6;
  if (lane == 0) sb[wid] = v;
  __syncthreads();
  float r = 0.f;
  if (threadIdx.x < 4) r = sb[threadIdx.x];
  r += __shfl_down(r, 2); r += __shfl_down(r, 1);
  __syncthreads();
  return r;   // valid on thread 0
}

__device__ inline float dot4(const float4& a, const float4& b) {
  return a.x*b.x + a.y*b.y + a.z*b.z + a.w*b.w;
}

// round-to-nearest-even bf16
__device__ inline unsigned short bhi(float x) {
  unsigned u = __float_as_uint(x);
  return (unsigned short)((u + 0x7fffu + ((u >> 16) & 1u)) >> 16);
}
__device__ inline ushort4 h4of(float4 f) {
  return make_ushort4(bhi(f.x), bhi(f.y), bhi(f.z), bhi(f.w));
}

// ---- fused prep: gather_ref (0..1023) | ne (1024..17407) | ss (17408..20479) ----
__global__ __launch_bounds__(256) void k_prep(const float* __restrict__ T,
                                              const float* __restrict__ Sf,
                                              const int* __restrict__ ref_perm,
                                              const int* __restrict__ shared_perm,
                                              float* __restrict__ ws) {
  __shared__ float sb[4];
  ushort* uws = (ushort*)(ws + FLOAT_END);
  int blk = blockIdx.x;
  int t = threadIdx.x;
  if (blk < 1024) {
    int b = blk >> 8, r = blk & 255;
    int pos = ref_perm[r];
    const float4* ts = (const float4*)(T  + ((size_t)(b*8 + 0)*PP + pos)*DD);
    const float4* sv = (const float4*)(Sf + ((size_t)(b*4 + 0)*PP + pos)*DD);
    float4 a = ts[t], c = sv[t];
    size_t base = ((size_t)b*RR + r)*DD + t*4;
    *(ushort4*)(uws + U_REF_T + base) = h4of(a);
    *(ushort4*)(uws + U_REF_S + base) = h4of(c);
    float r1 = block_sum256(dot4(a, a), sb);
    float r2 = block_sum256(dot4(c, c), sb);
    if (t == 0) {
      ws[OFF_RR_T + b*RR + r] = r1;
      ws[OFF_RR_S + b*RR + r] = r2;
    }
  } else if (blk < 17408) {
    int i = blk - 1024;
    int b = i >> 12, e = i & 4095;
    int f = 1 + 2*(e >> 10);
    int pos = e & 1023;
    const float4* src = (const float4*)(T + ((size_t)(b*8 + f)*PP + pos)*DD);
    float4 a = src[t];
    *(ushort4*)(uws + U_EXT + ((size_t)b*EE + e)*DD + t*4) = h4of(a);
    float tot = block_sum256(dot4(a, a), sb);
    if (t == 0) ws[OFF_NE + (size_t)b*EE + e] = fmaxf(sqrtf(tot), 1e-12f);
  } else {
    int idx = blk - 17408;                 // z*SSZ + s
    int p = idx / (BB*SSZ);
    int b = (idx / SSZ) % BB;
    int s = idx % SSZ;
    int pos = shared_perm[s];
    int ti = 2*(p + 1), si = p + 1;
    const float4* tr = (const float4*)(T  + ((size_t)(b*8 + ti)*PP + pos)*DD);
    const float4* sr = (const float4*)(Sf + ((size_t)(b*4 + si)*PP + pos)*DD);
    float4 a = tr[t], c = sr[t];
    size_t base = (size_t)idx*DD + t*4;
    *(ushort4*)(uws + U_SH_T + base) = h4of(a);
    *(ushort4*)(uws + U_SH_S + base) = h4of(c);
    float r1 = block_sum256(dot4(a, a), sb);
    float r2 = block_sum256(dot4(c, c), sb);
    if (t == 0) { ws[OFF_SS_T + idx] = r1; ws[OFF_SS_S + idx] = r2; }
  }
}

// ---- sim GEMM: 2-phase dbuf gload_lds staging + fused top-4, XCD-pinned ----
// 1-D grid 1024: d = u8 + 8*(e_t*2 + r_loc); unit u8 = b*2 + r_half -> XCD u8.
// Tile rows: [0..63] ref_t(r0+row), [64..127] ext(e0+row-64). BK=32, 32 steps.
__global__ __launch_bounds__(256) void k_sim(float* __restrict__ ws) {
  __shared__ union SM {
    ushort stg[2][128][32];    // 16 KB
    float simv[64][68];        // 17.4 KB epilogue
  } sm;
  const ushort* uws = (const ushort*)(ws + FLOAT_END);
  int d = blockIdx.x;
  int u8 = d & 7, q = d >> 3;
  int e_t = q >> 1, r_loc = q & 1;
  int b = u8 >> 1, rhalf = u8 & 1;
  int e0 = e_t * 64;
  int r0 = (rhalf*2 + r_loc) * 64;
  int tid = threadIdx.x;
  int w = tid >> 6, lane = tid & 63;
  int l15 = tid & 15, lq = (tid >> 4) & 3;

  const ushort* gsrc[2];
#pragma unroll
  for (int seg = 0; seg < 2; ++seg) {
    int rt = 32*w + 16*seg + (lane >> 2);
    const ushort* base; size_t rowg;
    if (rt < 64) { base = uws + U_REF_T; rowg = (size_t)(b*RR + r0 + rt); }
    else         { base = uws + U_EXT;   rowg = (size_t)(b*EE + e0 + rt - 64); }
    int c_log = (lane & 3) ^ ((rt >> 1) & 3);
    gsrc[seg] = base + rowg*DD + c_log*8;
  }

  // preload norms (before K-loop: keeps vmcnt bookkeeping clean)
  float invs[4];
#pragma unroll
  for (int j = 0; j < 4; ++j)
    invs[j] = 1.f / ws[OFF_NE + (size_t)b*EE + e0 + j*16 + l15];

  f32x4 acc[4];
#pragma unroll
  for (int j = 0; j < 4; ++j) acc[j] = (f32x4){0.f, 0.f, 0.f, 0.f};

  // prologue stage
  GLOAD_LDS(gsrc[0], &sm.stg[0][32*w][0]);
  GLOAD_LDS(gsrc[1], &sm.stg[0][32*w + 16][0]);
  gsrc[0] += 32; gsrc[1] += 32;

  int cur = 0;
#pragma unroll 1
  for (int k0 = 0; k0 < 32; ++k0) {
    if (k0 < 31) {
      GLOAD_LDS(gsrc[0], &sm.stg[cur ^ 1][32*w][0]);
      GLOAD_LDS(gsrc[1], &sm.stg[cur ^ 1][32*w + 16][0]);
      gsrc[0] += 32; gsrc[1] += 32;
      asm volatile("s_waitcnt vmcnt(2)" ::: "memory");
    } else {
      asm volatile("s_waitcnt vmcnt(0)" ::: "memory");
    }
    __builtin_amdgcn_s_barrier();
    __builtin_amdgcn_sched_barrier(0);
    int rtA = w*16 + l15;
    short8 ah = *(const short8*)&sm.stg[cur][rtA][(lq ^ ((rtA >> 1) & 3))*8];
#pragma unroll
    for (int j = 0; j < 4; ++j) {
      int rtB = 64 + j*16 + l15;
      short8 bh = *(const short8*)&sm.stg[cur][rtB][(lq ^ ((rtB >> 1) & 3))*8];
      acc[j] = MFMA16(ah, bh, acc[j]);
    }
    __builtin_amdgcn_sched_barrier(0);
    __builtin_amdgcn_s_barrier();
    cur ^= 1;
  }

#pragma unroll
  for (int j = 0; j < 4; ++j) {
    int e_loc = j*16 + l15;
#pragma unroll
    for (int q2 = 0; q2 < 4; ++q2)
      sm.simv[w*16 + lq*4 + q2][e_loc] = acc[j][q2] * invs[j];
  }
  __syncthreads();
  if (tid < 64) {
    float v[4] = {-FLT_MAX, -FLT_MAX, -FLT_MAX, -FLT_MAX};
    int ix[4] = {0x7fffffff, 0x7fffffff, 0x7fffffff, 0x7fffffff};
#pragma unroll 1
    for (int e = 0; e < 64; ++e) {
      float f = sm.simv[tid][e];
      if (f > v[3]) {
        int eg = e0 + e;
        if (f > v[0])      { v[3]=v[2]; ix[3]=ix[2]; v[2]=v[1]; ix[2]=ix[1]; v[1]=v[0]; ix[1]=ix[0]; v[0]=f; ix[0]=eg; }
        else if (f > v[1]) { v[3]=v[2]; ix[3]=ix[2]; v[2]=v[1]; ix[2]=ix[1]; v[1]=f; ix[1]=eg; }
        else if (f > v[2]) { v[3]=v[2]; ix[3]=ix[2]; v[2]=f; ix[2]=eg; }
        else               { v[3]=f; ix[3]=eg; }
      }
    }
    float2* cand = (float2*)(ws + OFF_CAND);
    size_t base = (((size_t)(b*RR + r0 + tid))*64 + e_t)*4;
#pragma unroll
    for (int k = 0; k < 4; ++k)
      cand[base + k] = make_float2(v[k], __int_as_float(ix[k]));
  }
}

// ---- merge 256 candidates -> top-4 per (b,r), ties -> lower global index ----
__global__ __launch_bounds__(256) void k_topk2(float* __restrict__ ws) {
  __shared__ float rv[256];
  __shared__ int   ri[256];
  __shared__ int   winIdx;
  int br = blockIdx.x;
  int tid = threadIdx.x;
  const float2* cand = (const float2*)(ws + OFF_CAND);
  float2 c = cand[(size_t)br*256 + tid];
  float v = c.x;
  int idx = __float_as_int(c.y);
  int* outi = (int*)(ws + OFF_TOPK) + (size_t)br*KT;
  for (int k = 0; k < KT; ++k) {
    rv[tid] = v; ri[tid] = idx;
    __syncthreads();
    for (int off = 128; off > 0; off >>= 1) {
      if (tid < off) {
        float v2 = rv[tid+off]; int i2 = ri[tid+off];
        if (v2 > rv[tid] || (v2 == rv[tid] && i2 < ri[tid])) { rv[tid] = v2; ri[tid] = i2; }
      }
      __syncthreads();
    }
    if (tid == 0) { outi[k] = ri[0]; winIdx = ri[0]; }
    __syncthreads();
    if (idx == winIdx) v = -FLT_MAX;
    __syncthreads();
  }
}

// ---- gather selected rows: bf16 store + hh / rh_t / rh_s (fp32) ----
__global__ __launch_bounds__(256) void k_gather_high(const float* __restrict__ T,
                                                     const float* __restrict__ Sf,
                                                     const int* __restrict__ ref_perm,
                                                     float* __restrict__ ws) {
  __shared__ float sb[4];
  int idx = blockIdx.x;                        // (b*RR + r)*KT + k
  int e = ((const int*)(ws + OFF_TOPK))[idx];
  int b = idx >> 10;
  int r = (idx >> 2) & 255;
  int rpos = ref_perm[r];
  const float4* src = (const float4*)(T + ((size_t)(b*8 + 1 + 2*(e >> 10))*PP + (e & 1023))*DD);
  const float4* rt  = (const float4*)(T  + ((size_t)(b*8 + 0)*PP + rpos)*DD);
  const float4* rs  = (const float4*)(Sf + ((size_t)(b*4 + 0)*PP + rpos)*DD);
  ushort* uws = (ushort*)(ws + FLOAT_END);
  int t = threadIdx.x;
  float4 h = src[t];
  *(ushort4*)(uws + U_SIMH + (size_t)idx*DD + t*4) = h4of(h);
  float4 a = rt[t], c = rs[t];
  float r1 = block_sum256(dot4(h, h), sb);
  float r2 = block_sum256(dot4(h, a), sb);
  float r3 = block_sum256(dot4(h, c), sb);
  if (t == 0) { ws[OFF_HH + idx] = r1; ws[OFF_RH_T + idx] = r2; ws[OFF_RH_S + idx] = r3; }
}

// ---- main fused kernel: 2-phase dbuf gload_lds staging, XCD-pinned units ----
// d = x + 8*(q + 32*uu): XCD x runs unit u = x + 8*uu (one 2.5MB unit at a time).
// u -> (z = u>>1, r-half = u&1); q -> (r_loc = q>>3, s_t = q&7).
// Tile rows: [0..127] simh, [128..159] ref_t, [160..191] ref_s,
//            [192..223] sh_t, [224..255] sh_s.  BK=32, 32 steps.
__global__ __launch_bounds__(512) void k_main(float* __restrict__ ws,
                                              double* __restrict__ acc_out) {
  __shared__ union SM {
    ushort stg[2][256][32];                                // 32 KB
    struct { float Ct[192][17]; float Cs2[192][17]; } c;   // 25.5 KB epilogue
  } sm;
  __shared__ float sb[8];
  const ushort* uws = (const ushort*)(ws + FLOAT_END);

  int d = blockIdx.x;
  int x  = d & 7;
  int t7 = d >> 3;             // 0..95
  int q  = t7 & 31;            // 0..31
  int uu = t7 >> 5;            // 0..2
  int u  = x + 8*uu;           // unit 0..23, pinned to XCD x
  int z = u >> 1;
  int b = z & 3;
  int r_t = (u & 1)*4 + (q >> 3);
  int s_t = q & 7;
  int s0 = s_t*32, r0 = r_t*32;
  int tid = threadIdx.x;
  int w = tid >> 6, lane = tid & 63;
  int l15 = tid & 15, lq = (tid >> 4) & 3;
  int mw = w & 3, nh = w >> 2;

  // staging sources: wave w covers tile rows 32w..32w+31
  const ushort* gsrc[2];
#pragma unroll
  for (int seg = 0; seg < 2; ++seg) {
    int rt = 32*w + 16*seg + (lane >> 2);
    int g = rt >> 4;
    const ushort* base; size_t rowg;
    if (g < 8)       { base = uws + U_SIMH;  rowg = (size_t)((b*RR + r0)*4 + rt); }
    else if (g < 10) { base = uws + U_REF_T; rowg = (size_t)(b*RR + r0 + rt - 128); }
    else if (g < 12) { base = uws + U_REF_S; rowg = (size_t)(b*RR + r0 + rt - 160); }
    else if (g < 14) { base = uws + U_SH_T;  rowg = (size_t)(z*SSZ + s0 + rt - 192); }
    else             { base = uws + U_SH_S;  rowg = (size_t)(z*SSZ + s0 + rt - 224); }
    int c_log = (lane & 3) ^ ((rt >> 1) & 3);
    gsrc[seg] = base + rowg*DD + c_log*8;
  }

  // ---- epilogue scalars preloaded BEFORE the K-loop (clean vmcnt) ----
  int rl = tid >> 4, sl = tid & 15;   // rl 0..31, sl 0..15
  int r = r0 + rl;
  float rrt = ws[OFF_RR_T + b*RR + r];
  float rrs = ws[OFF_RR_S + b*RR + r];
  float hhk[4], rhtk[4], rhsk[4], ihr_t[4], ihr_s[4];
#pragma unroll
  for (int k = 0; k < 4; ++k) {
    int idx = (b*RR + r)*KT + k;
    hhk[k]  = ws[OFF_HH + idx];
    rhtk[k] = ws[OFF_RH_T + idx];
    rhsk[k] = ws[OFF_RH_S + idx];
    float nt = sqrtf(fmaxf(hhk[k] - 2.f*rhtk[k] + rrt, 0.f));
    float ns = sqrtf(fmaxf(hhk[k] - 2.f*rhsk[k] + rrs, 0.f));
    ihr_t[k] = 1.f / fmaxf(nt, 1e-8f);
    ihr_s[k] = 1.f / fmaxf(ns, 1e-8f);
  }
  float sst2[2], sss2[2];
#pragma unroll
  for (int h = 0; h < 2; ++h) {
    int sidx = z*SSZ + s0 + h*16 + sl;
    sst2[h] = ws[OFF_SS_T + sidx];
    sss2[h] = ws[OFF_SS_S + sidx];
  }

  f32x4 acc[3][2];
#pragma unroll
  for (int i = 0; i < 3; ++i)
#pragma unroll
    for (int j = 0; j < 2; ++j) acc[i][j] = (f32x4){0.f, 0.f, 0.f, 0.f};

  // prologue stage into buf 0
  GLOAD_LDS(gsrc[0], &sm.stg[0][32*w][0]);
  GLOAD_LDS(gsrc[1], &sm.stg[0][32*w + 16][0]);
  gsrc[0] += 32; gsrc[1] += 32;

  int cur = 0;
#pragma unroll 1
  for (int k0 = 0; k0 < 32; ++k0) {
    if (k0 < 31) {
      GLOAD_LDS(gsrc[0], &sm.stg[cur ^ 1][32*w][0]);
      GLOAD_LDS(gsrc[1], &sm.stg[cur ^ 1][32*w + 16][0]);
      gsrc[0] += 32; gsrc[1] += 32;
      asm volatile("s_waitcnt vmcnt(2)" ::: "memory");
    } else {
      asm volatile("s_waitcnt vmcnt(0)" ::: "memory");
    }
    __builtin_amdgcn_s_barrier();
    __builtin_amdgcn_sched_barrier(0);
    short8 ah[3], bh[2];
#pragma unroll
    for (int i = 0; i < 3; ++i) {
      int rt = (3*mw + i)*16 + l15;
      ah[i] = *(const short8*)&sm.stg[cur][rt][(lq ^ ((rt >> 1) & 3))*8];
    }
#pragma unroll
    for (int j = 0; j < 2; ++j) {
      int rt = 192 + nh*32 + j*16 + l15;
      bh[j] = *(const short8*)&sm.stg[cur][rt][(lq ^ ((rt >> 1) & 3))*8];
    }
#pragma unroll
    for (int j = 0; j < 2; ++j)
#pragma unroll
      for (int i = 0; i < 3; ++i)
        acc[i][j] = MFMA16(ah[i], bh[j], acc[i][j]);
    __builtin_amdgcn_sched_barrier(0);
    __builtin_amdgcn_s_barrier();
    cur ^= 1;
  }

  float local = 0.f;
#pragma unroll
  for (int h = 0; h < 2; ++h) {
    __syncthreads();                 // prior LDS use done (stg/K-loop or pass 0)
#pragma unroll
    for (int i = 0; i < 3; ++i)
#pragma unroll
      for (int qq = 0; qq < 4; ++qq) {
        int row = (3*mw + i)*16 + lq*4 + qq;
        if (nh == 0) sm.c.Ct[row][l15]  = acc[i][h][qq];
        else         sm.c.Cs2[row][l15] = acc[i][h][qq];
      }
    __syncthreads();
    float sst = sst2[h];
    float sss = sss2[h];
    float srt = sm.c.Ct[128 + rl][sl];
    float srs = sm.c.Cs2[160 + rl][sl];
    float isr_t = 1.f / fmaxf(sqrtf(fmaxf(sst - 2.f*srt + rrt, 0.f)), 1e-8f);
    float isr_s = 1.f / fmaxf(sqrtf(fmaxf(sss - 2.f*srs + rrs, 0.f)), 1e-8f);
#pragma unroll
    for (int k = 0; k < 4; ++k) {
      float sht = sm.c.Ct[rl*4 + k][sl];
      float shs = sm.c.Cs2[rl*4 + k][sl];
      float ish_t = 1.f / fmaxf(sqrtf(fmaxf(sst - 2.f*sht + hhk[k], 0.f)), 1e-8f);
      float ish_s = 1.f / fmaxf(sqrtf(fmaxf(sss - 2.f*shs + hhk[k], 0.f)), 1e-8f);
      float a1t = (sht - rhtk[k] - srt + rrt) * (isr_t * ihr_t[k]);
      float a2t = (srt - sht - rhtk[k] + hhk[k]) * (ihr_t[k] * ish_t);
      float a3t = (rhtk[k] - srt - sht + sst) * (isr_t * ish_t);
      float a1s = (shs - rhsk[k] - srs + rrs) * (isr_s * ihr_s[k]);
      float a2s = (srs - shs - rhsk[k] + hhk[k]) * (ihr_s[k] * ish_s);
      float a3s = (rhsk[k] - srs - shs + sss) * (isr_s * ish_s);
      local += fabsf(a1s - a1t) + fabsf(a2s - a2t) + fabsf(a3s - a3t);
    }
  }

  // block sum over 512 threads
  float v = local;
  v += __shfl_down(v, 32); v += __shfl_down(v, 16);
  v += __shfl_down(v, 8);  v += __shfl_down(v, 4);
  v += __shfl_down(v, 2);  v += __shfl_down(v, 1);
  if ((tid & 63) == 0) sb[w] = v;
  __syncthreads();
  if (tid < 8) {
    float rsum = sb[tid];
    rsum += __shfl_down(rsum, 4);
    rsum += __shfl_down(rsum, 2);
    rsum += __shfl_down(rsum, 1);
    if (tid == 0) atomicAdd(acc_out, (double)rsum);
  }
}

__global__ void k_final(const double* __restrict__ acc, float* __restrict__ out) {
  out[0] = (float)(acc[0] / 3145728.0);   // 3 * B * R * S * K
}

extern "C" void kernel_launch(void* const* d_in, const int* in_sizes, int n_in,
                              void* d_out, int out_size, void* d_ws, size_t ws_size,
                              hipStream_t stream) {
  const float* T  = (const float*)d_in[0];
  const float* Sf = (const float*)d_in[1];
  const int* ref_perm    = (const int*)d_in[2];
  const int* shared_perm = (const int*)d_in[3];
  float* ws = (float*)d_ws;
  double* acc = (double*)(ws + OFF_ACC);

  hipMemsetAsync(acc, 0, sizeof(double), stream);
  k_prep<<<20480, 256, 0, stream>>>(T, Sf, ref_perm, shared_perm, ws);
  k_sim<<<1024, 256, 0, stream>>>(ws);
  k_topk2<<<BB*RR, 256, 0, stream>>>(ws);
  k_gather_high<<<BB*RR*KT, 256, 0, stream>>>(T, Sf, ref_perm, ws);
  k_main<<<768, 512, 0, stream>>>(ws, acc);
  k_final<<<1, 1, 0, stream>>>(acc, (float*)d_out);
}